// Round 1
// baseline (434.986 us; speedup 1.0000x reference)
//
#include <hip/hip_runtime.h>
#include <hip/hip_bf16.h>
#include <math.h>

// Problem constants
#define NNODES 10000
#define NEDGE  160000
// MULT=16, NL=2, DIM=4, EDGE_DIM=32, HID=128, RANK=8, H=4, HM=4

typedef unsigned short u16;
using bf16x8 = __attribute__((ext_vector_type(8))) short;
using f32x4  = __attribute__((ext_vector_type(4))) float;

static __device__ __forceinline__ u16 f2bf(float x) {
  unsigned u = __float_as_uint(x);
  u += 0x7FFFu + ((u >> 16) & 1u);     // RNE
  return (u16)(u >> 16);
}
static __device__ __forceinline__ float bf2f(u16 h) {
  return __uint_as_float(((unsigned)h) << 16);
}
// packed RNE f32x2 -> bf16x2 (gfx950 v_cvt_pk_bf16_f32 via HIP API)
static __device__ __forceinline__ unsigned pack_bf16(float a, float b) {
  __hip_bfloat162 h = __float22bfloat162_rn(make_float2(a, b));
  return *(unsigned*)&h;               // low = a, high = b
}
// tanh-form gelu: x*sigmoid(x*(1.5957691 + 0.0713548*x^2)); |err| < 5e-4 abs.
static __device__ __forceinline__ float fast_gelu(float x) {
  float y = x * __builtin_fmaf(0.07135481283f, x * x, 1.5957691216f);
  float e = __expf(y);
  return x - x * __builtin_amdgcn_rcpf(e + 1.0f);
}

// ---------------- fused setup: prep_w | prep_w1 | q | zero(num,den) ---------
// CSR machinery is GONE (no csr_build / fill_t): K+V run in one block and the
// attention reduction is done with device-scope f32 atomics, so edge order no
// longer matters. This kernel additionally zeroes the num/den accumulators.
__global__ void __launch_bounds__(256) setup_kernel(
    const float* __restrict__ kwr, const float* __restrict__ kwl,
    const float* __restrict__ vwr, const float* __restrict__ vwl,
    u16* __restrict__ Wsw,
    const float* __restrict__ kw1, const float* __restrict__ vw1,
    u16* __restrict__ W1sw,
    const float* __restrict__ f, const float* __restrict__ qw,
    const float* __restrict__ qb, float* __restrict__ q,
    float* __restrict__ zbase) {
  int b = blockIdx.x, tid = threadIdx.x;
  if (b < 512) {                      // prep_w
    int idx = b * 256 + tid;          // 0..131071  (4 slots x 32768)
    int slot = idx >> 15;
    int w = idx & 32767;
    int j = w & 7, lane = (w >> 3) & 63, ks = (w >> 9) & 3, tg = w >> 11;
    int k   = ks * 32 + ((lane >> 4) << 3) + j;
    int col = (tg << 4) + (lane & 15);
    const float* s = (slot == 0) ? kwr : (slot == 1) ? kwl : (slot == 2) ? vwr : vwl;
    Wsw[idx] = f2bf(s[k * 256 + col]);
  } else if (b < 544) {               // prep_w1
    int idx = (b - 512) * 256 + tid;  // 0..8191 (2 slots x 4096)
    int slot = idx >> 12;
    int w = idx & 4095;
    int j = w & 7, lane = (w >> 3) & 63, nt = w >> 9;
    int k   = ((lane >> 4) << 3) + j;
    int col = (nt << 4) + (lane & 15);
    const float* s = (slot == 0) ? kw1 : vw1;
    W1sw[idx] = f2bf(s[k * 128 + col]);
  } else if (b < 1169) {              // q: 625 blocks
    int i = (b - 544) * 256 + tid;    // n*16 + o
    if (i >= NNODES * 16) return;
    int n = i >> 4, o = i & 15;
    const float* frow = f + (size_t)n * 64;
    float o0 = 0.f, o1 = 0.f, o2 = 0.f, o3 = 0.f;
#pragma unroll
    for (int m = 0; m < 16; ++m) {
      float w0 = qw[o * 16 + m];
      float w1 = qw[(16 + o) * 16 + m];
      o0 += w0 * frow[m * 4 + 0];
      o1 += w1 * frow[m * 4 + 1];
      o2 += w1 * frow[m * 4 + 2];
      o3 += w1 * frow[m * 4 + 3];
    }
    o0 += qb[o];
    float4 r = make_float4(o0, o1, o2, o3);
    *(float4*)(q + (size_t)i * 4) = r;
  } else {                            // zero num+den: 665 blocks, float4 each
    int idx = (b - 1169) * 256 + tid; // 170000 float4 = 2,720,000 B
    if (idx < 170000)
      *(float4*)((char*)zbase + (size_t)idx * 16) = make_float4(0.f, 0.f, 0.f, 0.f);
  }
}

// ---------------- merged K+V equivariant conv + fused attention scatter -----
// One block per 64-edge tile (edge order, no CSR). Stages ef/t/b2/dst once,
// then runs the K conv (-> ex = exp(qk/4) into LDS) and the V conv
// (-> atomicAdd ex*v into num, ex into den). Body of each phase is the
// validated 64-VGPR round-12 conv structure (pointer selects are SGPR-only).
// NO min-wave launch bound (round 8/9: acc floor is 64 VGPRs; forcing 8
// waves/EU spilled 814 MB scratch).
__global__ void __launch_bounds__(512) convkv_kernel(
    const float* __restrict__ ef, const float* __restrict__ f,
    const float* __restrict__ b1, const float* __restrict__ b2,
    const int* __restrict__ src, const int* __restrict__ dst,
    const u16* __restrict__ w1sw_k, const float* __restrict__ b1h_k,
    const u16* __restrict__ wswr_k, const float* __restrict__ br_k,
    const u16* __restrict__ wswl_k, const float* __restrict__ bl_k,
    const u16* __restrict__ w1sw_v, const float* __restrict__ b1h_v,
    const u16* __restrict__ wswr_v, const float* __restrict__ br_v,
    const u16* __restrict__ wswl_v, const float* __restrict__ bl_v,
    const float* __restrict__ qbuf, float* __restrict__ num,
    float* __restrict__ den) {
  __shared__ alignas(16) u16 sA[64 * 136];       // H tile [edge][hid]
  __shared__ alignas(16) u16 t_s[64 * 40];       // t tile (bf16)
  __shared__ alignas(16) float b2_s[64 * 12];
  __shared__ alignas(16) float u_s[64 * 12];     // u[e][p]
  __shared__ alignas(16) float t2_pool[64 * 36]; // t2[e][r2]; overlays efs
  __shared__ float exs_s[64 * 4];                // ex from K phase
  __shared__ int   nn[64];                       // dst node per edge
  float* t2_s = t2_pool;
  u16*   efs  = (u16*)t2_pool;                   // ef tile bf16 [edge][k] pitch 40

  int tid = threadIdx.x;
  int wave = tid >> 6, lane = tid & 63, quad = lane >> 4, l16 = lane & 15;
  size_t i0 = (size_t)blockIdx.x * 64;
  int e8 = tid >> 3, j8 = tid & 7;               // 8 threads per edge

  // ---- stage: efs (f32->bf16), t (compute from f[src] x b1), b2, dst ----
  {
    float4 ev = *(const float4*)&ef[(i0 + e8) * 32 + j8 * 4];
    *(uint2*)&efs[e8 * 40 + j8 * 4] =
        make_uint2(pack_bf16(ev.x, ev.y), pack_bf16(ev.z, ev.w));
    int se = src[i0 + e8];
    const float* frow = f + (size_t)se * 64;
    const float* be = b1 + (i0 + e8) * 8;        // (4,2)
    float bb[8];
#pragma unroll
    for (int k = 0; k < 8; ++k) bb[k] = be[k];
    float4 a = *(const float4*)&frow[(2 * j8) * 4];
    float t0 = a.x * bb[0] + a.y * bb[2] + a.z * bb[4] + a.w * bb[6];
    float t1 = a.x * bb[1] + a.y * bb[3] + a.z * bb[5] + a.w * bb[7];
    float4 c = *(const float4*)&frow[(2 * j8 + 1) * 4];
    float t2a = c.x * bb[0] + c.y * bb[2] + c.z * bb[4] + c.w * bb[6];
    float t3a = c.x * bb[1] + c.y * bb[3] + c.z * bb[5] + c.w * bb[7];
    *(uint2*)&t_s[e8 * 40 + j8 * 4] =
        make_uint2(pack_bf16(t0, t1), pack_bf16(t2a, t3a));
    b2_s[e8 * 12 + j8] = b2[(i0 + e8) * 8 + j8];
    if (tid < 64) nn[tid] = dst[i0 + tid];
  }
  __syncthreads();

#pragma unroll 1
  for (int ph = 0; ph < 2; ++ph) {
    const u16*   w1sw  = ph ? w1sw_v : w1sw_k;
    const float* b1h   = ph ? b1h_v  : b1h_k;
    const u16*   wsw_r = ph ? wswr_v : wswr_k;
    const float* br    = ph ? br_v   : br_k;
    const u16*   wsw_l = ph ? wswl_v : wswl_k;
    const float* bl    = ph ? bl_v   : bl_k;

    if (ph == 1) {
      // K-final t2_s reads done -> safe to rebuild efs over t2_pool.
      __syncthreads();
      float4 ev = *(const float4*)&ef[(i0 + e8) * 32 + j8 * 4];  // L2-hot
      *(uint2*)&efs[e8 * 40 + j8 * 4] =
          make_uint2(pack_bf16(ev.x, ev.y), pack_bf16(ev.z, ev.w));
      __syncthreads();
    }

    // ---- h-stage: wave owns hid-tile `wave` (16 cols), 4 edge tiles ----
    {
      bf16x8 aw = *(const bf16x8*)&w1sw[(size_t)(wave * 64 + lane) * 8];  // A = w1^T
      float4 bias_h = *(const float4*)&b1h[wave * 16 + quad * 4];
#pragma unroll
      for (int nt = 0; nt < 4; ++nt) {
        bf16x8 bef = *(const bf16x8*)&efs[(nt * 16 + l16) * 40 + quad * 8]; // B = ef^T
        f32x4 acch = __builtin_amdgcn_mfma_f32_16x16x32_bf16(aw, bef, (f32x4){0.f, 0.f, 0.f, 0.f}, 0, 0, 0);
        unsigned p0 = pack_bf16(fast_gelu(acch[0] + bias_h.x), fast_gelu(acch[1] + bias_h.y));
        unsigned p1 = pack_bf16(fast_gelu(acch[2] + bias_h.z), fast_gelu(acch[3] + bias_h.w));
        *(uint2*)&sA[(nt * 16 + l16) * 136 + wave * 16 + quad * 4] = make_uint2(p0, p1);
      }
    }
    __syncthreads();

    // ---- K-loop: transposed GEMMs (A = weights, B = H), zero-seeded accs ----
    f32x4 accr[2][4], accl[2][4];
#pragma unroll
    for (int mtl = 0; mtl < 2; ++mtl)
#pragma unroll
      for (int nt = 0; nt < 4; ++nt) {
        accr[mtl][nt] = (f32x4){0.f, 0.f, 0.f, 0.f};
        accl[mtl][nt] = (f32x4){0.f, 0.f, 0.f, 0.f};
      }
#pragma unroll
    for (int ks = 0; ks < 4; ++ks) {
      bf16x8 bfrag[4];
#pragma unroll
      for (int nt = 0; nt < 4; ++nt)
        bfrag[nt] = *(const bf16x8*)&sA[(nt * 16 + l16) * 136 + ks * 32 + quad * 8];
#pragma unroll
      for (int mtl = 0; mtl < 2; ++mtl) {
        int mtg = wave * 2 + mtl;
        bf16x8 ar = *(const bf16x8*)&wsw_r[(size_t)((mtg * 4 + ks) * 64 + lane) * 8];
        bf16x8 al = *(const bf16x8*)&wsw_l[(size_t)((mtg * 4 + ks) * 64 + lane) * 8];
#pragma unroll
        for (int nt = 0; nt < 4; ++nt) {
          accr[mtl][nt] = __builtin_amdgcn_mfma_f32_16x16x32_bf16(ar, bfrag[nt], accr[mtl][nt], 0, 0, 0);
          accl[mtl][nt] = __builtin_amdgcn_mfma_f32_16x16x32_bf16(al, bfrag[nt], accl[mtl][nt], 0, 0, 0);
        }
      }
    }

    // ---- bias preloads: weight-col = (2w+mtl)*16 + 4q + r ----
    float4 brv[2], blv[2];
#pragma unroll
    for (int mtl = 0; mtl < 2; ++mtl) {
      int colb = (wave * 2 + mtl) * 16 + quad * 4;
      brv[mtl] = *(const float4*)&br[colb];
      blv[mtl] = *(const float4*)&bl[colb];
    }

    // ---- right epilogue: u[e, p=wave] = sum_c (right+br)*t ----
#pragma unroll
    for (int nt = 0; nt < 4; ++nt) {
      int e = nt * 16 + l16;
      ushort4 ta = *(const ushort4*)&t_s[e * 40 + 4 * quad];        // c: mtl=0
      ushort4 tb = *(const ushort4*)&t_s[e * 40 + 16 + 4 * quad];   // c: mtl=1
      float s = (accr[0][nt][0] + brv[0].x) * bf2f(ta.x)
              + (accr[0][nt][1] + brv[0].y) * bf2f(ta.y)
              + (accr[0][nt][2] + brv[0].z) * bf2f(ta.z)
              + (accr[0][nt][3] + brv[0].w) * bf2f(ta.w)
              + (accr[1][nt][0] + brv[1].x) * bf2f(tb.x)
              + (accr[1][nt][1] + brv[1].y) * bf2f(tb.y)
              + (accr[1][nt][2] + brv[1].z) * bf2f(tb.z)
              + (accr[1][nt][3] + brv[1].w) * bf2f(tb.w);
      s += __shfl_xor(s, 16);
      s += __shfl_xor(s, 32);
      if (quad == 0) u_s[e * 12 + wave] = s;
    }
    __syncthreads();   // u_s ready; efs reads long done -> t2_s overlay safe

    // ---- left epilogue: t2[e, r2] = sum_p (left+bl)*u ----
#pragma unroll
    for (int nt = 0; nt < 4; ++nt) {
      int e = nt * 16 + l16;
      float4 uv = *(const float4*)&u_s[e * 12 + 4 * (quad & 1)];
#pragma unroll
      for (int mtl = 0; mtl < 2; ++mtl) {
        float s = (accl[mtl][nt][0] + blv[mtl].x) * uv.x
                + (accl[mtl][nt][1] + blv[mtl].y) * uv.y
                + (accl[mtl][nt][2] + blv[mtl].z) * uv.z
                + (accl[mtl][nt][3] + blv[mtl].w) * uv.w;
        s += __shfl_xor(s, 16);                    // combine p halves (q^1)
        if ((quad & 1) == 0)
          t2_s[e * 36 + 4 * wave + 2 * mtl + (quad >> 1)] = s;
      }
    }
    __syncthreads();

    // ---- final stage: thread -> (e8, j8), elems j8*8..j8*8+7 ----
    {
      float4 t2 = *(const float4*)&t2_s[e8 * 36 + 4 * j8];   // r2 = 4j..4j+3
      float4 b2a = *(const float4*)&b2_s[e8 * 12 + 0];
      float4 b2b = *(const float4*)&b2_s[e8 * 12 + 4];
      float v0 = t2.x * b2a.x + t2.y * b2b.x;   // m=2j,   d=0..3
      float v1 = t2.x * b2a.y + t2.y * b2b.y;
      float v2 = t2.x * b2a.z + t2.y * b2b.z;
      float v3 = t2.x * b2a.w + t2.y * b2b.w;
      float v4 = t2.z * b2a.x + t2.w * b2b.x;   // m=2j+1, d=0..3
      float v5 = t2.z * b2a.y + t2.w * b2b.y;
      float v6 = t2.z * b2a.z + t2.w * b2b.z;
      float v7 = t2.z * b2a.w + t2.w * b2b.w;
      int n = nn[e8];
      if (ph == 0) {
        // K: head (j>>1) half-dot with q, pair-combine, exp, stash in LDS
        const float* qr = qbuf + (size_t)n * 64 + j8 * 8;
        float4 qa = *(const float4*)&qr[0];
        float4 qc = *(const float4*)&qr[4];
        float s = v0 * qa.x + v1 * qa.y + v2 * qa.z + v3 * qa.w
                + v4 * qc.x + v5 * qc.y + v6 * qc.z + v7 * qc.w;
        s += __shfl_xor(s, 1);                     // combine the two half-heads
        if ((j8 & 1) == 0)
          exs_s[e8 * 4 + (j8 >> 1)] = __expf(s * 0.25f);
      } else {
        // V: fused attention scatter (fire-and-forget f32 atomics)
        float ex = exs_s[e8 * 4 + (j8 >> 1)];
        float* np = num + (size_t)n * 64 + j8 * 8;
        atomicAdd(&np[0], ex * v0);
        atomicAdd(&np[1], ex * v1);
        atomicAdd(&np[2], ex * v2);
        atomicAdd(&np[3], ex * v3);
        atomicAdd(&np[4], ex * v4);
        atomicAdd(&np[5], ex * v5);
        atomicAdd(&np[6], ex * v6);
        atomicAdd(&np[7], ex * v7);
        if ((j8 & 1) == 0)
          atomicAdd(&den[n * 4 + (j8 >> 1)], ex);
      }
    }
  }
}

// ---------------- divide: out = num / max(den, 1e-9) ------------------------
__global__ void __launch_bounds__(256) divide_kernel(
    const float* __restrict__ num, const float* __restrict__ den,
    float* __restrict__ outp) {
  int idx = blockIdx.x * 256 + threadIdx.x;   // 160000 exact (one float4 each)
  int n = idx >> 4, g = idx & 15;             // head = g>>2
  float d = den[n * 4 + (g >> 2)];
  float r = 1.0f / fmaxf(d, 1e-9f);
  float4 v = *(const float4*)&num[(size_t)idx * 4];
  float4 o = make_float4(v.x * r, v.y * r, v.z * r, v.w * r);
  *(float4*)&outp[(size_t)idx * 4] = o;
}

extern "C" void kernel_launch(void* const* d_in, const int* in_sizes, int n_in,
                              void* d_out, int out_size, void* d_ws, size_t ws_size,
                              hipStream_t stream) {
  const float* b1  = (const float*)d_in[0];
  const float* b2  = (const float*)d_in[1];
  const float* ef  = (const float*)d_in[2];
  const float* f   = (const float*)d_in[3];
  const int*   src = (const int*)d_in[4];
  const int*   dst = (const int*)d_in[5];
  const float* qw  = (const float*)d_in[6];
  const float* qb  = (const float*)d_in[7];
  const float* kw1 = (const float*)d_in[8];
  const float* kb1 = (const float*)d_in[9];
  const float* kwl = (const float*)d_in[10];
  const float* kbl = (const float*)d_in[11];
  const float* kwr = (const float*)d_in[12];
  const float* kbr = (const float*)d_in[13];
  const float* vw1 = (const float*)d_in[14];
  const float* vb1 = (const float*)d_in[15];
  const float* vwl = (const float*)d_in[16];
  const float* vbl = (const float*)d_in[17];
  const float* vwr = (const float*)d_in[18];
  const float* vbr = (const float*)d_in[19];
  float* outp = (float*)d_out;

  // workspace layout
  char* ws = (char*)d_ws;
  size_t off = 0;
  auto alloc = [&](size_t bytes) {
    char* p = ws + off;
    off += (bytes + 511) & ~(size_t)511;
    return p;
  };
  u16*   Wsw  = (u16*)  alloc((size_t)4 * 32768 * 2);
  u16*   W1sw = (u16*)  alloc((size_t)2 * 4096 * 2);
  float* qbuf = (float*)alloc((size_t)NNODES * 64 * 4);
  float* numb = (float*)alloc((size_t)NNODES * 64 * 4);   // 2,560,000 B (512-mult)
  float* denb = (float*)alloc((size_t)NNODES * 4 * 4);    // contiguous after numb

  // setup: prep_w | prep_w1 | q | zero(num+den = 170000 float4)
  setup_kernel<<<1834, 256, 0, stream>>>(kwr, kwl, vwr, vwl, Wsw,
                                         kw1, vw1, W1sw,
                                         f, qw, qb, qbuf, numb);

  // merged K+V conv with fused attention scatter (2500 tiles of 64 edges)
  convkv_kernel<<<2500, 512, 0, stream>>>(ef, f, b1, b2, src, dst,
                                          W1sw + 0 * 4096, kb1,
                                          Wsw + 0 * 32768, kbr,
                                          Wsw + 1 * 32768, kbl,
                                          W1sw + 1 * 4096, vb1,
                                          Wsw + 2 * 32768, vbr,
                                          Wsw + 3 * 32768, vbl,
                                          qbuf, numb, denb);

  // normalize
  divide_kernel<<<625, 256, 0, stream>>>(numb, denb, outp);
}

// Round 2
// 267.081 us; speedup vs baseline: 1.6287x; 1.6287x over previous
//
#include <hip/hip_runtime.h>
#include <hip/hip_bf16.h>
#include <math.h>

// Problem constants
#define NNODES 10000
#define NEDGE  160000
// MULT=16, NL=2, DIM=4, EDGE_DIM=32, HID=128, RANK=8, H=4, HM=4

typedef unsigned short u16;
using bf16x8 = __attribute__((ext_vector_type(8))) short;
using f32x4  = __attribute__((ext_vector_type(4))) float;

static __device__ __forceinline__ u16 f2bf(float x) {
  unsigned u = __float_as_uint(x);
  u += 0x7FFFu + ((u >> 16) & 1u);     // RNE
  return (u16)(u >> 16);
}
static __device__ __forceinline__ float bf2f(u16 h) {
  return __uint_as_float(((unsigned)h) << 16);
}
// packed RNE f32x2 -> bf16x2 (gfx950 v_cvt_pk_bf16_f32 via HIP API)
static __device__ __forceinline__ unsigned pack_bf16(float a, float b) {
  __hip_bfloat162 h = __float22bfloat162_rn(make_float2(a, b));
  return *(unsigned*)&h;               // low = a, high = b
}
// tanh-form gelu: x*sigmoid(x*(1.5957691 + 0.0713548*x^2)); |err| < 5e-4 abs.
static __device__ __forceinline__ float fast_gelu(float x) {
  float y = x * __builtin_fmaf(0.07135481283f, x * x, 1.5957691216f);
  float e = __expf(y);
  return x - x * __builtin_amdgcn_rcpf(e + 1.0f);
}

// ---------------- CSR build: histogram + scan in ONE single-block kernel ----
// LESSON (round 1): 10.9M device-scope f32 atomics = 325 MB write-through
// (per-XCD L2 can't absorb coherent RMW) -> 4x regression. CSR + streaming
// gather is the right reduction; only 160K slot atomics remain (in convkv).
__global__ void __launch_bounds__(1024) csr_build_kernel(
    const int* __restrict__ dst, int* __restrict__ rowptr, int* __restrict__ cursor) {
  __shared__ int hist[NNODES];       // 40000 B
  __shared__ int part[1024];         //  4096 B
  int t = threadIdx.x;
  for (int i = t; i < NNODES; i += 1024) hist[i] = 0;
  __syncthreads();
  const int4* d4 = (const int4*)dst; // NEDGE/4 = 40000 int4s, coalesced
  for (int i = t; i < NEDGE / 4; i += 1024) {
    int4 v = d4[i];
    atomicAdd(&hist[v.x], 1);
    atomicAdd(&hist[v.y], 1);
    atomicAdd(&hist[v.z], 1);
    atomicAdd(&hist[v.w], 1);
  }
  __syncthreads();
  int base = t * 10;                 // 1024*10 = 10240 >= NNODES
  int local[10];
  int s = 0;
#pragma unroll
  for (int i = 0; i < 10; ++i) {
    int idx = base + i;
    local[i] = (idx < NNODES) ? hist[idx] : 0;
    s += local[i];
  }
  part[t] = s;
  __syncthreads();
  for (int o = 1; o < 1024; o <<= 1) {
    int v = (t >= o) ? part[t - o] : 0;
    __syncthreads();
    part[t] += v;
    __syncthreads();
  }
  int run = (t == 0) ? 0 : part[t - 1];
#pragma unroll
  for (int i = 0; i < 10; ++i) {
    int idx = base + i;
    if (idx < NNODES) { rowptr[idx] = run; cursor[idx] = run; run += local[i]; }
  }
  if (t == 1023) rowptr[NNODES] = run;
}

// ---------------- fused setup: prep_w | prep_w1 | q --------------------------
__global__ void __launch_bounds__(256) setup_kernel(
    const float* __restrict__ kwr, const float* __restrict__ kwl,
    const float* __restrict__ vwr, const float* __restrict__ vwl,
    u16* __restrict__ Wsw,
    const float* __restrict__ kw1, const float* __restrict__ vw1,
    u16* __restrict__ W1sw,
    const float* __restrict__ f, const float* __restrict__ qw,
    const float* __restrict__ qb, float* __restrict__ q) {
  int b = blockIdx.x, tid = threadIdx.x;
  if (b < 512) {                      // prep_w
    int idx = b * 256 + tid;          // 0..131071  (4 slots x 32768)
    int slot = idx >> 15;
    int w = idx & 32767;
    int j = w & 7, lane = (w >> 3) & 63, ks = (w >> 9) & 3, tg = w >> 11;
    int k   = ks * 32 + ((lane >> 4) << 3) + j;
    int col = (tg << 4) + (lane & 15);
    const float* s = (slot == 0) ? kwr : (slot == 1) ? kwl : (slot == 2) ? vwr : vwl;
    Wsw[idx] = f2bf(s[k * 256 + col]);
  } else if (b < 544) {               // prep_w1
    int idx = (b - 512) * 256 + tid;  // 0..8191 (2 slots x 4096)
    int slot = idx >> 12;
    int w = idx & 4095;
    int j = w & 7, lane = (w >> 3) & 63, nt = w >> 9;
    int k   = ((lane >> 4) << 3) + j;
    int col = (nt << 4) + (lane & 15);
    const float* s = (slot == 0) ? kw1 : vw1;
    W1sw[idx] = f2bf(s[k * 128 + col]);
  } else {                            // q: 625 blocks
    int i = (b - 544) * 256 + tid;    // n*16 + o
    if (i >= NNODES * 16) return;
    int n = i >> 4, o = i & 15;
    const float* frow = f + (size_t)n * 64;
    float o0 = 0.f, o1 = 0.f, o2 = 0.f, o3 = 0.f;
#pragma unroll
    for (int m = 0; m < 16; ++m) {
      float w0 = qw[o * 16 + m];
      float w1 = qw[(16 + o) * 16 + m];
      o0 += w0 * frow[m * 4 + 0];
      o1 += w1 * frow[m * 4 + 1];
      o2 += w1 * frow[m * 4 + 2];
      o3 += w1 * frow[m * 4 + 3];
    }
    o0 += qb[o];
    float4 r = make_float4(o0, o1, o2, o3);
    *(float4*)(q + (size_t)i * 4) = r;
  }
}

// ---------------- merged K+V equivariant conv, CSR-slotted outputs ----------
// One block per 64-edge tile. Stages ef/t/b2/dst directly from inputs (no
// comb buffer, no fill_t pass), runs the K conv (-> ex = exp(qk/4) into LDS
// and exs[pos]), then the V conv (-> bf16 kv row at kv[pos]). pos is the
// edge's CSR slot from a 1-per-edge cursor atomic (160K atomics total: fine;
// 10.9M was not). Body of each phase is the validated 64-VGPR structure
// (pointer selects are SGPR-only). NO min-wave launch bound (round 8/9: acc
// floor is 64 VGPRs; forcing 8 waves/EU spilled 814 MB scratch).
__global__ void __launch_bounds__(512) convkv_kernel(
    const float* __restrict__ ef, const float* __restrict__ f,
    const float* __restrict__ b1, const float* __restrict__ b2,
    const int* __restrict__ src, const int* __restrict__ dst,
    const u16* __restrict__ w1sw_k, const float* __restrict__ b1h_k,
    const u16* __restrict__ wswr_k, const float* __restrict__ br_k,
    const u16* __restrict__ wswl_k, const float* __restrict__ bl_k,
    const u16* __restrict__ w1sw_v, const float* __restrict__ b1h_v,
    const u16* __restrict__ wswr_v, const float* __restrict__ br_v,
    const u16* __restrict__ wswl_v, const float* __restrict__ bl_v,
    const float* __restrict__ qbuf, int* __restrict__ cursor,
    float* __restrict__ exs, u16* __restrict__ kv) {
  __shared__ alignas(16) u16 sA[64 * 136];       // H tile [edge][hid]
  __shared__ alignas(16) u16 t_s[64 * 40];       // t tile (bf16)
  __shared__ alignas(16) float b2_s[64 * 12];
  __shared__ alignas(16) float u_s[64 * 12];     // u[e][p]
  __shared__ alignas(16) float t2_pool[64 * 36]; // t2[e][r2]; overlays efs
  __shared__ float exs_s[64 * 4];                // ex from K phase
  __shared__ int   nn[64];                       // dst node per edge
  __shared__ int   pos_s[64];                    // CSR slot per edge
  float* t2_s = t2_pool;
  u16*   efs  = (u16*)t2_pool;                   // ef tile bf16 [edge][k] pitch 40

  int tid = threadIdx.x;
  int wave = tid >> 6, lane = tid & 63, quad = lane >> 4, l16 = lane & 15;
  size_t i0 = (size_t)blockIdx.x * 64;
  int e8 = tid >> 3, j8 = tid & 7;               // 8 threads per edge

  // ---- stage: efs (f32->bf16), t (compute from f[src] x b1), b2, dst/pos ----
  {
    float4 ev = *(const float4*)&ef[(i0 + e8) * 32 + j8 * 4];
    *(uint2*)&efs[e8 * 40 + j8 * 4] =
        make_uint2(pack_bf16(ev.x, ev.y), pack_bf16(ev.z, ev.w));
    int se = src[i0 + e8];
    const float* frow = f + (size_t)se * 64;
    const float* be = b1 + (i0 + e8) * 8;        // (4,2)
    float bb[8];
#pragma unroll
    for (int k = 0; k < 8; ++k) bb[k] = be[k];
    float4 a = *(const float4*)&frow[(2 * j8) * 4];
    float t0 = a.x * bb[0] + a.y * bb[2] + a.z * bb[4] + a.w * bb[6];
    float t1 = a.x * bb[1] + a.y * bb[3] + a.z * bb[5] + a.w * bb[7];
    float4 c = *(const float4*)&frow[(2 * j8 + 1) * 4];
    float t2a = c.x * bb[0] + c.y * bb[2] + c.z * bb[4] + c.w * bb[6];
    float t3a = c.x * bb[1] + c.y * bb[3] + c.z * bb[5] + c.w * bb[7];
    *(uint2*)&t_s[e8 * 40 + j8 * 4] =
        make_uint2(pack_bf16(t0, t1), pack_bf16(t2a, t3a));
    b2_s[e8 * 12 + j8] = b2[(i0 + e8) * 8 + j8];
    if (tid < 64) {
      int n = dst[i0 + tid];
      nn[tid] = n;
      pos_s[tid] = atomicAdd(&cursor[n], 1);
    }
  }
  __syncthreads();

#pragma unroll 1
  for (int ph = 0; ph < 2; ++ph) {
    const u16*   w1sw  = ph ? w1sw_v : w1sw_k;
    const float* b1h   = ph ? b1h_v  : b1h_k;
    const u16*   wsw_r = ph ? wswr_v : wswr_k;
    const float* br    = ph ? br_v   : br_k;
    const u16*   wsw_l = ph ? wswl_v : wswl_k;
    const float* bl    = ph ? bl_v   : bl_k;

    if (ph == 1) {
      // K-final t2_s reads done -> safe to rebuild efs over t2_pool.
      __syncthreads();
      float4 ev = *(const float4*)&ef[(i0 + e8) * 32 + j8 * 4];  // L2-hot
      *(uint2*)&efs[e8 * 40 + j8 * 4] =
          make_uint2(pack_bf16(ev.x, ev.y), pack_bf16(ev.z, ev.w));
      __syncthreads();
    }

    // ---- h-stage: wave owns hid-tile `wave` (16 cols), 4 edge tiles ----
    {
      bf16x8 aw = *(const bf16x8*)&w1sw[(size_t)(wave * 64 + lane) * 8];  // A = w1^T
      float4 bias_h = *(const float4*)&b1h[wave * 16 + quad * 4];
#pragma unroll
      for (int nt = 0; nt < 4; ++nt) {
        bf16x8 bef = *(const bf16x8*)&efs[(nt * 16 + l16) * 40 + quad * 8]; // B = ef^T
        f32x4 acch = __builtin_amdgcn_mfma_f32_16x16x32_bf16(aw, bef, (f32x4){0.f, 0.f, 0.f, 0.f}, 0, 0, 0);
        unsigned p0 = pack_bf16(fast_gelu(acch[0] + bias_h.x), fast_gelu(acch[1] + bias_h.y));
        unsigned p1 = pack_bf16(fast_gelu(acch[2] + bias_h.z), fast_gelu(acch[3] + bias_h.w));
        *(uint2*)&sA[(nt * 16 + l16) * 136 + wave * 16 + quad * 4] = make_uint2(p0, p1);
      }
    }
    __syncthreads();

    // ---- K-loop: transposed GEMMs (A = weights, B = H), zero-seeded accs ----
    f32x4 accr[2][4], accl[2][4];
#pragma unroll
    for (int mtl = 0; mtl < 2; ++mtl)
#pragma unroll
      for (int nt = 0; nt < 4; ++nt) {
        accr[mtl][nt] = (f32x4){0.f, 0.f, 0.f, 0.f};
        accl[mtl][nt] = (f32x4){0.f, 0.f, 0.f, 0.f};
      }
#pragma unroll
    for (int ks = 0; ks < 4; ++ks) {
      bf16x8 bfrag[4];
#pragma unroll
      for (int nt = 0; nt < 4; ++nt)
        bfrag[nt] = *(const bf16x8*)&sA[(nt * 16 + l16) * 136 + ks * 32 + quad * 8];
#pragma unroll
      for (int mtl = 0; mtl < 2; ++mtl) {
        int mtg = wave * 2 + mtl;
        bf16x8 ar = *(const bf16x8*)&wsw_r[(size_t)((mtg * 4 + ks) * 64 + lane) * 8];
        bf16x8 al = *(const bf16x8*)&wsw_l[(size_t)((mtg * 4 + ks) * 64 + lane) * 8];
#pragma unroll
        for (int nt = 0; nt < 4; ++nt) {
          accr[mtl][nt] = __builtin_amdgcn_mfma_f32_16x16x32_bf16(ar, bfrag[nt], accr[mtl][nt], 0, 0, 0);
          accl[mtl][nt] = __builtin_amdgcn_mfma_f32_16x16x32_bf16(al, bfrag[nt], accl[mtl][nt], 0, 0, 0);
        }
      }
    }

    // ---- bias preloads: weight-col = (2w+mtl)*16 + 4q + r ----
    float4 brv[2], blv[2];
#pragma unroll
    for (int mtl = 0; mtl < 2; ++mtl) {
      int colb = (wave * 2 + mtl) * 16 + quad * 4;
      brv[mtl] = *(const float4*)&br[colb];
      blv[mtl] = *(const float4*)&bl[colb];
    }

    // ---- right epilogue: u[e, p=wave] = sum_c (right+br)*t ----
#pragma unroll
    for (int nt = 0; nt < 4; ++nt) {
      int e = nt * 16 + l16;
      ushort4 ta = *(const ushort4*)&t_s[e * 40 + 4 * quad];        // c: mtl=0
      ushort4 tb = *(const ushort4*)&t_s[e * 40 + 16 + 4 * quad];   // c: mtl=1
      float s = (accr[0][nt][0] + brv[0].x) * bf2f(ta.x)
              + (accr[0][nt][1] + brv[0].y) * bf2f(ta.y)
              + (accr[0][nt][2] + brv[0].z) * bf2f(ta.z)
              + (accr[0][nt][3] + brv[0].w) * bf2f(ta.w)
              + (accr[1][nt][0] + brv[1].x) * bf2f(tb.x)
              + (accr[1][nt][1] + brv[1].y) * bf2f(tb.y)
              + (accr[1][nt][2] + brv[1].z) * bf2f(tb.z)
              + (accr[1][nt][3] + brv[1].w) * bf2f(tb.w);
      s += __shfl_xor(s, 16);
      s += __shfl_xor(s, 32);
      if (quad == 0) u_s[e * 12 + wave] = s;
    }
    __syncthreads();   // u_s ready; efs reads long done -> t2_s overlay safe

    // ---- left epilogue: t2[e, r2] = sum_p (left+bl)*u ----
#pragma unroll
    for (int nt = 0; nt < 4; ++nt) {
      int e = nt * 16 + l16;
      float4 uv = *(const float4*)&u_s[e * 12 + 4 * (quad & 1)];
#pragma unroll
      for (int mtl = 0; mtl < 2; ++mtl) {
        float s = (accl[mtl][nt][0] + blv[mtl].x) * uv.x
                + (accl[mtl][nt][1] + blv[mtl].y) * uv.y
                + (accl[mtl][nt][2] + blv[mtl].z) * uv.z
                + (accl[mtl][nt][3] + blv[mtl].w) * uv.w;
        s += __shfl_xor(s, 16);                    // combine p halves (q^1)
        if ((quad & 1) == 0)
          t2_s[e * 36 + 4 * wave + 2 * mtl + (quad >> 1)] = s;
      }
    }
    __syncthreads();

    // ---- final stage: thread -> (e8, j8), elems j8*8..j8*8+7 ----
    {
      float4 t2 = *(const float4*)&t2_s[e8 * 36 + 4 * j8];   // r2 = 4j..4j+3
      float4 b2a = *(const float4*)&b2_s[e8 * 12 + 0];
      float4 b2b = *(const float4*)&b2_s[e8 * 12 + 4];
      float v0 = t2.x * b2a.x + t2.y * b2b.x;   // m=2j,   d=0..3
      float v1 = t2.x * b2a.y + t2.y * b2b.y;
      float v2 = t2.x * b2a.z + t2.y * b2b.z;
      float v3 = t2.x * b2a.w + t2.y * b2b.w;
      float v4 = t2.z * b2a.x + t2.w * b2b.x;   // m=2j+1, d=0..3
      float v5 = t2.z * b2a.y + t2.w * b2b.y;
      float v6 = t2.z * b2a.z + t2.w * b2b.z;
      float v7 = t2.z * b2a.w + t2.w * b2b.w;
      int pos = pos_s[e8];
      if (ph == 0) {
        // K: head (j>>1) half-dot with q, pair-combine, exp -> LDS + exs[pos]
        int n = nn[e8];
        const float* qr = qbuf + (size_t)n * 64 + j8 * 8;
        float4 qa = *(const float4*)&qr[0];
        float4 qc = *(const float4*)&qr[4];
        float s = v0 * qa.x + v1 * qa.y + v2 * qa.z + v3 * qa.w
                + v4 * qc.x + v5 * qc.y + v6 * qc.z + v7 * qc.w;
        s += __shfl_xor(s, 1);                     // combine the two half-heads
        if ((j8 & 1) == 0) {
          float ex = __expf(s * 0.25f);
          exs_s[e8 * 4 + (j8 >> 1)] = ex;
          exs[(size_t)pos * 4 + (j8 >> 1)] = ex;   // 4 lanes -> one 16B line
        }
      } else {
        // V: pack bf16 kv row into its CSR slot (128B contiguous per edge)
        unsigned q0 = pack_bf16(v0, v1);
        unsigned q1 = pack_bf16(v2, v3);
        unsigned q2 = pack_bf16(v4, v5);
        unsigned q3 = pack_bf16(v6, v7);
        *(uint4*)&kv[(size_t)pos * 64 + j8 * 8] = make_uint4(q0, q1, q2, q3);
      }
    }
  }
}

// ---------------- attention gather: pure streaming weighted sum -------------
// ex precomputed by conv-K; per edge: num += ex*v, den += ex. No shuffles/exp.
__global__ void __launch_bounds__(256) attn_gather_kernel(
    const float* __restrict__ exs, const u16* __restrict__ kvv,
    const int* __restrict__ rowptr, float* __restrict__ outp) {
  int tid = threadIdx.x;
  int node = blockIdx.x * 4 + (tid >> 6);        // grid 2500 * 4 = NNODES
  int lane = tid & 63, h = lane >> 4;
  int beg = rowptr[node], end = rowptr[node + 1];
  float num = 0.f, den = 0.f;
  int idx = beg;
  for (; idx + 2 <= end; idx += 2) {
    float e0 = exs[(size_t)idx * 4 + h];
    float e1 = exs[(size_t)(idx + 1) * 4 + h];
    float v0 = bf2f(kvv[(size_t)idx * 64 + lane]);
    float v1 = bf2f(kvv[(size_t)(idx + 1) * 64 + lane]);
    num += e0 * v0 + e1 * v1;
    den += e0 + e1;
  }
  if (idx < end) {
    float e0 = exs[(size_t)idx * 4 + h];
    num += e0 * bf2f(kvv[(size_t)idx * 64 + lane]);
    den += e0;
  }
  outp[(size_t)node * 64 + lane] = num / fmaxf(den, 1e-9f);
}

extern "C" void kernel_launch(void* const* d_in, const int* in_sizes, int n_in,
                              void* d_out, int out_size, void* d_ws, size_t ws_size,
                              hipStream_t stream) {
  const float* b1  = (const float*)d_in[0];
  const float* b2  = (const float*)d_in[1];
  const float* ef  = (const float*)d_in[2];
  const float* f   = (const float*)d_in[3];
  const int*   src = (const int*)d_in[4];
  const int*   dst = (const int*)d_in[5];
  const float* qw  = (const float*)d_in[6];
  const float* qb  = (const float*)d_in[7];
  const float* kw1 = (const float*)d_in[8];
  const float* kb1 = (const float*)d_in[9];
  const float* kwl = (const float*)d_in[10];
  const float* kbl = (const float*)d_in[11];
  const float* kwr = (const float*)d_in[12];
  const float* kbr = (const float*)d_in[13];
  const float* vw1 = (const float*)d_in[14];
  const float* vb1 = (const float*)d_in[15];
  const float* vwl = (const float*)d_in[16];
  const float* vbl = (const float*)d_in[17];
  const float* vwr = (const float*)d_in[18];
  const float* vbr = (const float*)d_in[19];
  float* outp = (float*)d_out;

  // workspace layout
  char* ws = (char*)d_ws;
  size_t off = 0;
  auto alloc = [&](size_t bytes) {
    char* p = ws + off;
    off += (bytes + 511) & ~(size_t)511;
    return p;
  };
  u16*   Wsw  = (u16*)  alloc((size_t)4 * 32768 * 2);
  u16*   W1sw = (u16*)  alloc((size_t)2 * 4096 * 2);
  float* qbuf = (float*)alloc((size_t)NNODES * 64 * 4);
  u16*   kvv  = (u16*)  alloc((size_t)NEDGE * 64 * 2);
  float* exb  = (float*)alloc((size_t)NEDGE * 4 * 4);
  int*   rowptr = (int*)alloc((size_t)(NNODES + 1) * 4);
  int*   cursor = (int*)alloc((size_t)NNODES * 4);

  // CSR build: one single-block kernel (histogram + scan)
  csr_build_kernel<<<1, 1024, 0, stream>>>(dst, rowptr, cursor);
  // setup: prep_w | prep_w1 | q
  setup_kernel<<<1169, 256, 0, stream>>>(kwr, kwl, vwr, vwl, Wsw,
                                         kw1, vw1, W1sw,
                                         f, qw, qb, qbuf);

  // merged K+V conv with CSR-slotted outputs (2500 tiles of 64 edges)
  convkv_kernel<<<2500, 512, 0, stream>>>(ef, f, b1, b2, src, dst,
                                          W1sw + 0 * 4096, kb1,
                                          Wsw + 0 * 32768, kbr,
                                          Wsw + 1 * 32768, kbl,
                                          W1sw + 1 * 4096, vb1,
                                          Wsw + 2 * 32768, vbr,
                                          Wsw + 3 * 32768, vbl,
                                          qbuf, cursor, exb, kvv);

  // attention: pure streaming weighted sum + divide
  attn_gather_kernel<<<2500, 256, 0, stream>>>(exb, kvv, rowptr, outp);
}